// Round 1
// baseline (219.109 us; speedup 1.0000x reference)
//
#include <hip/hip_runtime.h>
#include <stdint.h>

// MHA fwd: B=2, N=2048, D=1024, H=16, HD=64, scale=0.125
#define B_ 2
#define N_ 2048
#define D_ 1024
#define H_ 16

typedef unsigned short u16;
using f32x4  = __attribute__((ext_vector_type(4))) float;
using bf16x8 = __attribute__((ext_vector_type(8))) short;   // 8 bf16 bit-patterns (4 VGPRs)
using i16x8  = __attribute__((ext_vector_type(8))) short;

// fp32 -> bf16 (RNE) on bit level; all bf16 storage is u16
__device__ __forceinline__ u16 f2b(float f) {
  unsigned u = __float_as_uint(f);
  return (u16)((u + 0x7FFFu + ((u >> 16) & 1u)) >> 16);
}

__device__ __forceinline__ void async16(const u16* g, u16* l) {
  __builtin_amdgcn_global_load_lds(
      (const __attribute__((address_space(1))) void*)g,
      (__attribute__((address_space(3))) void*)l, 16, 0, 0);
}

__global__ __launch_bounds__(256) void cast8(const float* __restrict__ src,
                                             u16* __restrict__ dst, int n) {
  int i = (blockIdx.x * 256 + threadIdx.x) * 8;
  if (i >= n) return;
  i16x8 o;
#pragma unroll
  for (int j = 0; j < 8; ++j) o[j] = (short)f2b(src[i + j]);
  *(i16x8*)(dst + i) = o;
}

// C[M][Nn] = A[M][K] * Bt[Nn][K]^T   (both operands K-contiguous, NT GEMM)
// 128x128 tile, BK=32, 4 waves (2x2), each wave 64x64 via 4x4 frags of 16x16x32.
template <int F32OUT>
__global__ __launch_bounds__(256) void gemm_bt(
    const u16* __restrict__ A, const u16* __restrict__ Bt0, size_t sBz,
    void* __restrict__ C0, size_t sCz, const float* __restrict__ bias,
    int M, int Nn, int K) {
  __shared__ __align__(16) u16 As[128 * 32];
  __shared__ __align__(16) u16 Bs[128 * 32];
  const int tid = threadIdx.x;
  const int w = tid >> 6, l = tid & 63;
  const int wm = w >> 1, wn = w & 1;
  const int la = l & 15, lb = l >> 4;
  const int tM = blockIdx.y * 128, tN = blockIdx.x * 128;
  const u16* Bt = Bt0 + sBz * blockIdx.z;

  // staging: wave w covers rows 16w..16w+15 of each 64-row half; lane l -> row +(l>>2), k byte (l&3)*16
  const int sr = (w << 4) + (l >> 2);
  const int sk = (l & 3) << 3;
  const u16* gA = A + (size_t)(tM + sr) * K + sk;
  const u16* gB = Bt + (size_t)(tN + sr) * K + sk;
  u16* lA = As + w * 512;   // wave-uniform LDS dest (hw adds lane*16B)
  u16* lB = Bs + w * 512;

  f32x4 acc[4][4] = {};

  for (int k0 = 0; k0 < K; k0 += 32) {
    async16(gA, lA);
    async16(gA + (size_t)64 * K, lA + 2048);
    async16(gB, lB);
    async16(gB + (size_t)64 * K, lB + 2048);
    gA += 32; gB += 32;
    __syncthreads();   // drains vmcnt: tiles ready
    bf16x8 af[4], bfr[4];
#pragma unroll
    for (int i = 0; i < 4; ++i) {
      af[i]  = *(const bf16x8*)(As + (wm * 64 + i * 16 + la) * 32 + lb * 8);
      bfr[i] = *(const bf16x8*)(Bs + (wn * 64 + i * 16 + la) * 32 + lb * 8);
    }
#pragma unroll
    for (int i = 0; i < 4; ++i)
#pragma unroll
      for (int j = 0; j < 4; ++j)
        acc[i][j] = __builtin_amdgcn_mfma_f32_16x16x32_bf16(af[i], bfr[j], acc[i][j], 0, 0, 0);
    __syncthreads();   // before next stage overwrites
  }

#pragma unroll
  for (int i = 0; i < 4; ++i) {
    const int row = tM + wm * 64 + i * 16 + lb * 4;
#pragma unroll
    for (int j = 0; j < 4; ++j) {
      const int col = tN + wn * 64 + j * 16 + la;
#pragma unroll
      for (int r = 0; r < 4; ++r) {
        const float v = acc[i][j][r];
        if (F32OUT) {
          ((float*)C0)[(size_t)(row + r) * Nn + col] = v + bias[col];
        } else {
          (((u16*)C0) + sCz * blockIdx.z)[(size_t)(row + r) * Nn + col] = f2b(v);
        }
      }
    }
  }
}

// Flash attention: grid (N/64, B*H), 256 thr (4 waves x 16 query rows).
// K LDS tile XOR-swizzled via pre-swizzled global source (global_load_lds dest must be linear).
// V staged transposed (Vt[d][key], swizzled) so PV B-operand is a contiguous row read.
__global__ __launch_bounds__(256) void attn_fused(
    const u16* __restrict__ Q, const u16* __restrict__ Kb,
    const u16* __restrict__ Vb, u16* __restrict__ O) {
  __shared__ __align__(16) u16 Ks[64 * 64];
  __shared__ __align__(16) u16 Vt[64 * 64];
  __shared__ __align__(16) u16 Pl[4 * 16 * 64];
  const int tid = threadIdx.x;
  const int w = tid >> 6, l = tid & 63;
  const int la = l & 15, lb = l >> 4;
  const int b = blockIdx.y >> 4, h = blockIdx.y & 15;
  const int q0 = blockIdx.x * 64;

  // Q fragment held in registers for the whole KV loop
  const u16* Qrow = Q + (size_t)(b * N_ + q0 + w * 16 + la) * D_ + h * 64;
  bf16x8 qf0 = *(const bf16x8*)(Qrow + lb * 8);
  bf16x8 qf1 = *(const bf16x8*)(Qrow + 32 + lb * 8);

  const u16* Kg = Kb + (size_t)(b * N_) * D_ + h * 64;
  const u16* Vg = Vb + (size_t)(b * N_) * D_ + h * 64;

  const int krow = w * 16 + (l >> 3);                  // K-staging row (call0; call1 = +8)
  const int kcol_s = (((l & 7) ^ (l >> 3)) << 3);      // pre-swizzled source column

  const int vkey = tid >> 2;                           // V-staging: key, d-chunk
  const int vd0 = (tid & 3) * 16;

  float m_r[4], l_r[4];
  f32x4 oacc[4] = {};
#pragma unroll
  for (int r = 0; r < 4; ++r) { m_r[r] = -1e30f; l_r[r] = 0.f; }

  u16* Pw = Pl + w * 1024;  // per-wave P tile [16 q][64 k], swizzled

  for (int kv0 = 0; kv0 < N_; kv0 += 64) {
    // stage K (async, swizzled source -> linear dest == swizzled tile)
    async16(Kg + (size_t)(kv0 + krow) * D_ + kcol_s, Ks + w * 1024);
    async16(Kg + (size_t)(kv0 + krow + 8) * D_ + kcol_s, Ks + w * 1024 + 512);
    // stage V transposed
    {
      const u16* vs = Vg + (size_t)(kv0 + vkey) * D_ + vd0;
      i16x8 t0 = *(const i16x8*)(vs);
      i16x8 t1 = *(const i16x8*)(vs + 8);
#pragma unroll
      for (int i = 0; i < 8; ++i) {
        const int d = vd0 + i;
        Vt[d * 64 + (vkey ^ ((d & 7) << 3))] = (u16)t0[i];
      }
#pragma unroll
      for (int i = 8; i < 16; ++i) {
        const int d = vd0 + i;
        Vt[d * 64 + (vkey ^ ((d & 7) << 3))] = (u16)t1[i - 8];
      }
    }
    __syncthreads();

    // S = Q K^T  (16 queries x 64 keys per wave)
    f32x4 s[4] = {};
#pragma unroll
    for (int j = 0; j < 4; ++j) {
      const int row = j * 16 + la;
      const int sw = (la & 7) << 3;
      bf16x8 kf0 = *(const bf16x8*)(Ks + row * 64 + ((lb * 8) ^ sw));
      bf16x8 kf1 = *(const bf16x8*)(Ks + row * 64 + ((32 + lb * 8) ^ sw));
      s[j] = __builtin_amdgcn_mfma_f32_16x16x32_bf16(qf0, kf0, s[j], 0, 0, 0);
      s[j] = __builtin_amdgcn_mfma_f32_16x16x32_bf16(qf1, kf1, s[j], 0, 0, 0);
    }
#pragma unroll
    for (int j = 0; j < 4; ++j)
#pragma unroll
      for (int r = 0; r < 4; ++r) s[j][r] *= 0.125f;

    // online softmax: row (lb*4+r) stats live in the 16 lanes sharing lb
    float mnew[4], alpha[4];
#pragma unroll
    for (int r = 0; r < 4; ++r) {
      float mt = fmaxf(fmaxf(s[0][r], s[1][r]), fmaxf(s[2][r], s[3][r]));
#pragma unroll
      for (int off = 1; off < 16; off <<= 1) mt = fmaxf(mt, __shfl_xor(mt, off, 64));
      mnew[r] = fmaxf(m_r[r], mt);
      alpha[r] = __expf(m_r[r] - mnew[r]);
      m_r[r] = mnew[r];
    }
#pragma unroll
    for (int j = 0; j < 4; ++j)
#pragma unroll
      for (int r = 0; r < 4; ++r) s[j][r] = __expf(s[j][r] - mnew[r]);
#pragma unroll
    for (int r = 0; r < 4; ++r) {
      float rs = s[0][r] + s[1][r] + s[2][r] + s[3][r];
#pragma unroll
      for (int off = 1; off < 16; off <<= 1) rs += __shfl_xor(rs, off, 64);
      l_r[r] = l_r[r] * alpha[r] + rs;
    }
#pragma unroll
    for (int nd = 0; nd < 4; ++nd)
#pragma unroll
      for (int r = 0; r < 4; ++r) oacc[nd][r] *= alpha[r];

    // P -> LDS (swizzled, per-wave region; same-wave write->read ordered by lgkmcnt)
#pragma unroll
    for (int j = 0; j < 4; ++j)
#pragma unroll
      for (int r = 0; r < 4; ++r) {
        const int prow = lb * 4 + r;
        Pw[prow * 64 + ((j * 16 + la) ^ ((prow & 7) << 3))] = f2b(s[j][r]);
      }
    asm volatile("s_waitcnt lgkmcnt(0)" ::: "memory");

    // O += P V
#pragma unroll
    for (int ks = 0; ks < 2; ++ks) {
      bf16x8 pf = *(const bf16x8*)(Pw + la * 64 + ((ks * 32 + lb * 8) ^ ((la & 7) << 3)));
#pragma unroll
      for (int nd = 0; nd < 4; ++nd) {
        const int vrow = nd * 16 + la;
        bf16x8 vf = *(const bf16x8*)(Vt + vrow * 64 + ((ks * 32 + lb * 8) ^ ((la & 7) << 3)));
        oacc[nd] = __builtin_amdgcn_mfma_f32_16x16x32_bf16(pf, vf, oacc[nd], 0, 0, 0);
      }
    }
    __syncthreads();
  }

  u16* Ob = O + (size_t)(b * N_ + q0 + w * 16 + lb * 4) * D_ + h * 64;
#pragma unroll
  for (int nd = 0; nd < 4; ++nd)
#pragma unroll
    for (int r = 0; r < 4; ++r)
      Ob[(size_t)r * D_ + nd * 16 + la] = f2b(oacc[nd][r] / l_r[r]);
}

extern "C" void kernel_launch(void* const* d_in, const int* in_sizes, int n_in,
                              void* d_out, int out_size, void* d_ws, size_t ws_size,
                              hipStream_t stream) {
  const float* x  = (const float*)d_in[0];
  const float* Wq = (const float*)d_in[1];
  const float* Wk = (const float*)d_in[2];
  const float* Wv = (const float*)d_in[3];
  const float* Wo = (const float*)d_in[4];
  const float* bo = (const float*)d_in[5];
  float* out = (float*)d_out;

  char* ws = (char*)d_ws;
  u16* xb  = (u16*)(ws);                    //  8 MiB: x bf16 [4096][1024]
  u16* Wb  = (u16*)(ws + (8ull << 20));     //  8 MiB: Wq,Wk,Wv,Wo bf16 [4][1024][1024]
  u16* QKV = (u16*)(ws + (16ull << 20));    // 24 MiB: Q,K,V bf16 [3][4096][1024]
  u16* Ob  = (u16*)(ws + (40ull << 20));    //  8 MiB: attn out bf16 [4096][1024]

  cast8<<<dim3(2048), dim3(256), 0, stream>>>(x, xb, 4096 * 1024);
  cast8<<<dim3(512), dim3(256), 0, stream>>>(Wq, Wb + 0 * 1048576, 1048576);
  cast8<<<dim3(512), dim3(256), 0, stream>>>(Wk, Wb + 1 * 1048576, 1048576);
  cast8<<<dim3(512), dim3(256), 0, stream>>>(Wv, Wb + 2 * 1048576, 1048576);
  cast8<<<dim3(512), dim3(256), 0, stream>>>(Wo, Wb + 3 * 1048576, 1048576);

  // Q/K/V = x @ W^T  (z selects weight + output)
  gemm_bt<0><<<dim3(8, 32, 3), dim3(256), 0, stream>>>(
      xb, Wb, (size_t)1048576, QKV, (size_t)(4096 * 1024), (const float*)nullptr,
      4096, 1024, 1024);

  attn_fused<<<dim3(32, 32), dim3(256), 0, stream>>>(
      QKV, QKV + 4096 * 1024, QKV + 2 * 4096 * 1024, Ob);

  // out = attn @ Wo^T + bo  (fp32 out)
  gemm_bt<1><<<dim3(8, 32, 1), dim3(256), 0, stream>>>(
      Ob, Wb + 3 * 1048576, (size_t)0, out, (size_t)0, bo, 4096, 1024, 1024);
}

// Round 2
// 180.669 us; speedup vs baseline: 1.2128x; 1.2128x over previous
//
#include <hip/hip_runtime.h>
#include <hip/hip_bf16.h>
#include <stdint.h>

// MHA fwd: B=2, N=2048, D=1024, H=16, HD=64, scale=0.125
#define B_ 2
#define N_ 2048
#define D_ 1024
#define H_ 16
#define SCALE_L2E 0.18033688011112042f  // 0.125 * log2(e): Q pre-scaled -> softmax in base-2 domain

typedef unsigned short u16;
typedef unsigned int u32;
using f32x4  = __attribute__((ext_vector_type(4))) float;
using f32x16 = __attribute__((ext_vector_type(16))) float;
using bf16x8 = __attribute__((ext_vector_type(8))) short;   // 8 bf16 bit-patterns (4 VGPRs)
using i16x8  = __attribute__((ext_vector_type(8))) short;

// fp32 -> bf16 (RNE) bit-level
__device__ __forceinline__ u16 f2b(float f) {
  unsigned u = __float_as_uint(f);
  return (u16)((u + 0x7FFFu + ((u >> 16) & 1u)) >> 16);
}
// pack two f32 -> u32 of 2 bf16 (lo, hi) via hw cvt_pk
__device__ __forceinline__ u32 pk2(float lo, float hi) {
  __hip_bfloat162 h = __float22bfloat162_rn(float2{lo, hi});
  return *reinterpret_cast<u32*>(&h);
}

__device__ __forceinline__ void async16(const u16* g, u16* l) {
  __builtin_amdgcn_global_load_lds(
      (const __attribute__((address_space(1))) void*)g,
      (__attribute__((address_space(3))) void*)l, 16, 0, 0);
}

__global__ __launch_bounds__(256) void cast8(const float* __restrict__ src,
                                             u16* __restrict__ dst, int n) {
  int i = (blockIdx.x * 256 + threadIdx.x) * 8;
  if (i >= n) return;
  i16x8 o;
#pragma unroll
  for (int j = 0; j < 8; ++j) o[j] = (short)f2b(src[i + j]);
  *(i16x8*)(dst + i) = o;
}

// C[M][Nn] = A[M][K] * Bt[Nn][K]^T   (NT GEMM). 128x128 tile, BK=32, 4 waves.
// F32OUT==0: bf16 out; blockIdx.z==0 output scaled by SCALE_L2E (Q pre-scale).
template <int F32OUT>
__global__ __launch_bounds__(256) void gemm_bt(
    const u16* __restrict__ A, const u16* __restrict__ Bt0, size_t sBz,
    void* __restrict__ C0, size_t sCz, const float* __restrict__ bias,
    int M, int Nn, int K) {
  __shared__ __align__(16) u16 As[128 * 32];
  __shared__ __align__(16) u16 Bs[128 * 32];
  const int tid = threadIdx.x;
  const int w = tid >> 6, l = tid & 63;
  const int wm = w >> 1, wn = w & 1;
  const int la = l & 15, lb = l >> 4;
  const int tM = blockIdx.y * 128, tN = blockIdx.x * 128;
  const u16* Bt = Bt0 + sBz * blockIdx.z;

  const int sr = (w << 4) + (l >> 2);
  const int sk = (l & 3) << 3;
  const u16* gA = A + (size_t)(tM + sr) * K + sk;
  const u16* gB = Bt + (size_t)(tN + sr) * K + sk;
  u16* lA = As + w * 512;
  u16* lB = Bs + w * 512;

  f32x4 acc[4][4] = {};

  for (int k0 = 0; k0 < K; k0 += 32) {
    async16(gA, lA);
    async16(gA + (size_t)64 * K, lA + 2048);
    async16(gB, lB);
    async16(gB + (size_t)64 * K, lB + 2048);
    gA += 32; gB += 32;
    __syncthreads();
    bf16x8 af[4], bfr[4];
#pragma unroll
    for (int i = 0; i < 4; ++i) {
      af[i]  = *(const bf16x8*)(As + (wm * 64 + i * 16 + la) * 32 + lb * 8);
      bfr[i] = *(const bf16x8*)(Bs + (wn * 64 + i * 16 + la) * 32 + lb * 8);
    }
#pragma unroll
    for (int i = 0; i < 4; ++i)
#pragma unroll
      for (int j = 0; j < 4; ++j)
        acc[i][j] = __builtin_amdgcn_mfma_f32_16x16x32_bf16(af[i], bfr[j], acc[i][j], 0, 0, 0);
    __syncthreads();
  }

  const float osc = (!F32OUT && blockIdx.z == 0) ? SCALE_L2E : 1.0f;
#pragma unroll
  for (int i = 0; i < 4; ++i) {
    const int row = tM + wm * 64 + i * 16 + lb * 4;
#pragma unroll
    for (int j = 0; j < 4; ++j) {
      const int col = tN + wn * 64 + j * 16 + la;
#pragma unroll
      for (int r = 0; r < 4; ++r) {
        const float v = acc[i][j][r];
        if (F32OUT) {
          ((float*)C0)[(size_t)(row + r) * Nn + col] = v + bias[col];
        } else {
          (((u16*)C0) + sCz * blockIdx.z)[(size_t)(row + r) * Nn + col] = f2b(v * osc);
        }
      }
    }
  }
}

// Flash attention, swapped-QK^T 32x32 structure.
// grid (N/64, B*H), 128 thr = 2 waves x 32 queries. KV tile = 64.
// Lane: q = l&31 (query col), hi = l>>5. S^T=K*Q^T -> lane holds 32 P vals of
// one query; softmax in-register (log2 domain, Q pre-scaled by 0.125*log2e);
// P feeds PV B-operand via cvt_pk + shfl_xor(32) half-exchange (no P LDS).
__global__ __launch_bounds__(128) void attn_fused(
    const u16* __restrict__ Q, const u16* __restrict__ Kb,
    const u16* __restrict__ Vb, u16* __restrict__ O) {
  __shared__ __align__(16) u16 Ks[64 * 64];  // [key][d], cols XOR-swizzled by (key&7)<<3
  __shared__ __align__(16) u16 Vt[64 * 64];  // [d][key], cols XOR-swizzled by (d&7)<<3
  const int tid = threadIdx.x;
  const int w = tid >> 6, l = tid & 63;
  const int q = l & 31, hi = l >> 5;
  const int b = blockIdx.y >> 4, h = blockIdx.y & 15;
  const int q0 = blockIdx.x * 64 + w * 32;

  // Q fragments (B operand): qf[s] elem e = Q[q][16s + 8hi + e]
  const u16* Qrow = Q + (size_t)(b * N_ + q0 + q) * D_ + h * 64;
  bf16x8 qf[4];
#pragma unroll
  for (int s = 0; s < 4; ++s) qf[s] = *(const bf16x8*)(Qrow + s * 16 + hi * 8);

  const u16* Kg = Kb + (size_t)(b * N_) * D_ + h * 64;
  const u16* Vg = Vb + (size_t)(b * N_) * D_ + h * 64;

  // K staging: wave w rows [w*32, w*32+32), 4 async16 calls of 8 rows
  const int krow = w * 32 + (l >> 3);
  const int kcol_s = ((l & 7) ^ ((l >> 3) & 7)) << 3;  // pre-swizzled source col
  u16* lKbase = Ks + w * 2048;

  // V staging: kp = l&31 (key pair), chunks vc = w*2+hi and +4
  const int kp = q;
  const int qsw = (q & 7) << 3;   // read-side swizzle (rows d/key ≡ q mod 8 in both tiles)
  const int qr0 = q * 64, qr1 = (32 + q) * 64;

  float m_r = -1e30f, l_r = 0.f;
  f32x16 o0 = {}, o1 = {};

  for (int kv0 = 0; kv0 < N_; kv0 += 64) {
    // --- stage K (async DMA, swizzled via source) ---
#pragma unroll
    for (int c = 0; c < 4; ++c)
      async16(Kg + (size_t)(kv0 + krow + c * 8) * D_ + kcol_s, lKbase + c * 512);
    // --- stage V transposed (2 keys packed per u32 write; 2-way banks only) ---
#pragma unroll
    for (int cs = 0; cs < 2; ++cs) {
      const int vc = w * 2 + hi + cs * 4;
      const u16* vs = Vg + (size_t)(kv0 + 2 * kp) * D_ + vc * 8;
      i16x8 r0 = *(const i16x8*)(vs);
      i16x8 r1 = *(const i16x8*)(vs + D_);
#pragma unroll
      for (int i = 0; i < 8; ++i) {                 // d = vc*8+i, d&7 == i
        const int col = (2 * kp) ^ (i << 3);
        *(u32*)&Vt[(vc * 8 + i) * 64 + col] = (u32)(u16)r0[i] | ((u32)(u16)r1[i] << 16);
      }
    }
    __syncthreads();

    // --- S^T = K Q^T : lane q col, keys rows ---
    f32x16 p0 = {}, p1 = {};
    __builtin_amdgcn_s_setprio(1);
#pragma unroll
    for (int s = 0; s < 4; ++s) {
      const int c0 = s * 16 + hi * 8;
      bf16x8 kf0 = *(const bf16x8*)(Ks + qr0 + (c0 ^ qsw));
      bf16x8 kf1 = *(const bf16x8*)(Ks + qr1 + (c0 ^ qsw));
      p0 = __builtin_amdgcn_mfma_f32_32x32x16_bf16(kf0, qf[s], p0, 0, 0, 0);
      p1 = __builtin_amdgcn_mfma_f32_32x32x16_bf16(kf1, qf[s], p1, 0, 0, 0);
    }
    __builtin_amdgcn_s_setprio(0);

    // --- online softmax (log2 domain), stats pair-shared via shfl_xor(32) ---
    float pm = p0[0];
#pragma unroll
    for (int r = 1; r < 16; ++r) pm = fmaxf(pm, p0[r]);
#pragma unroll
    for (int r = 0; r < 16; ++r) pm = fmaxf(pm, p1[r]);
    pm = fmaxf(pm, __shfl_xor(pm, 32, 64));
    if (__any(pm > m_r + 8.f)) {           // T13 defer-max
      const float mn = fmaxf(m_r, pm);
      const float alpha = exp2f(m_r - mn);
      m_r = mn;
      l_r *= alpha;
#pragma unroll
      for (int r = 0; r < 16; ++r) { o0[r] *= alpha; o1[r] *= alpha; }
    }
#pragma unroll
    for (int r = 0; r < 16; ++r) p0[r] = exp2f(p0[r] - m_r);
#pragma unroll
    for (int r = 0; r < 16; ++r) p1[r] = exp2f(p1[r] - m_r);
    float rs = 0.f;
#pragma unroll
    for (int r = 0; r < 16; ++r) rs += p0[r] + p1[r];
    rs += __shfl_xor(rs, 32, 64);
    l_r += rs;

    // --- pack P -> PV B-frags: elem e of lane(q,hi) = reg (e&3)+8p+4hi from half e>>2 ---
    u32 pw[4][4];
#pragma unroll
    for (int ks = 0; ks < 4; ++ks) {
      const f32x16& P = (ks < 2) ? p0 : p1;   // kb = ks>>1 (folds: ks is unroll-const)
      const int rb = (ks & 1) * 8;
      const u32 A0 = pk2(P[rb + 0], P[rb + 1]);
      const u32 B0 = pk2(P[rb + 2], P[rb + 3]);
      const u32 A1 = pk2(P[rb + 4], P[rb + 5]);
      const u32 B1 = pk2(P[rb + 6], P[rb + 7]);
      const u32 v1 = hi ? A0 : A1, v2 = hi ? B0 : B1;
      const u32 sv1 = (u32)__shfl_xor((int)v1, 32, 64);
      const u32 sv2 = (u32)__shfl_xor((int)v2, 32, 64);
      pw[ks][0] = hi ? sv1 : A0;  pw[ks][1] = hi ? sv2 : B0;
      pw[ks][2] = hi ? A1 : sv1;  pw[ks][3] = hi ? B1 : sv2;
    }

    // --- O^T += V^T P^T ---
    __builtin_amdgcn_s_setprio(1);
#pragma unroll
    for (int ks = 0; ks < 4; ++ks) {
      union { u32 u[4]; bf16x8 v; } pb;
#pragma unroll
      for (int j = 0; j < 4; ++j) pb.u[j] = pw[ks][j];
      const int c0 = ks * 16 + hi * 8;
      bf16x8 va0 = *(const bf16x8*)(Vt + qr0 + (c0 ^ qsw));
      bf16x8 va1 = *(const bf16x8*)(Vt + qr1 + (c0 ^ qsw));
      o0 = __builtin_amdgcn_mfma_f32_32x32x16_bf16(va0, pb.v, o0, 0, 0, 0);
      o1 = __builtin_amdgcn_mfma_f32_32x32x16_bf16(va1, pb.v, o1, 0, 0, 0);
    }
    __builtin_amdgcn_s_setprio(0);
    __syncthreads();
  }

  // epilogue: O[q][d] = o/l ; lane's d = 32*df + 8*rh + 4*hi + (0..3)
  const float inv = 1.f / l_r;
  u16* Ob = O + (size_t)(b * N_ + q0 + q) * D_ + h * 64;
#pragma unroll
  for (int rh = 0; rh < 4; ++rh) {
    uint2 s0, s1;
    s0.x = pk2(o0[4 * rh + 0] * inv, o0[4 * rh + 1] * inv);
    s0.y = pk2(o0[4 * rh + 2] * inv, o0[4 * rh + 3] * inv);
    s1.x = pk2(o1[4 * rh + 0] * inv, o1[4 * rh + 1] * inv);
    s1.y = pk2(o1[4 * rh + 2] * inv, o1[4 * rh + 3] * inv);
    *(uint2*)(Ob + 8 * rh + 4 * hi)      = s0;
    *(uint2*)(Ob + 32 + 8 * rh + 4 * hi) = s1;
  }
}

extern "C" void kernel_launch(void* const* d_in, const int* in_sizes, int n_in,
                              void* d_out, int out_size, void* d_ws, size_t ws_size,
                              hipStream_t stream) {
  const float* x  = (const float*)d_in[0];
  const float* Wq = (const float*)d_in[1];
  const float* Wk = (const float*)d_in[2];
  const float* Wv = (const float*)d_in[3];
  const float* Wo = (const float*)d_in[4];
  const float* bo = (const float*)d_in[5];
  float* out = (float*)d_out;

  char* ws = (char*)d_ws;
  u16* xb  = (u16*)(ws);                    //  8 MiB: x bf16 [4096][1024]
  u16* Wb  = (u16*)(ws + (8ull << 20));     //  8 MiB: Wq,Wk,Wv,Wo bf16
  u16* QKV = (u16*)(ws + (16ull << 20));    // 24 MiB: Q,K,V bf16
  u16* Ob  = (u16*)(ws + (40ull << 20));    //  8 MiB: attn out bf16

  cast8<<<dim3(2048), dim3(256), 0, stream>>>(x, xb, 4096 * 1024);
  cast8<<<dim3(512), dim3(256), 0, stream>>>(Wq, Wb + 0 * 1048576, 1048576);
  cast8<<<dim3(512), dim3(256), 0, stream>>>(Wk, Wb + 1 * 1048576, 1048576);
  cast8<<<dim3(512), dim3(256), 0, stream>>>(Wv, Wb + 2 * 1048576, 1048576);
  cast8<<<dim3(512), dim3(256), 0, stream>>>(Wo, Wb + 3 * 1048576, 1048576);

  // Q/K/V = x @ W^T  (z selects weight + output; z==0 output pre-scaled)
  gemm_bt<0><<<dim3(8, 32, 3), dim3(256), 0, stream>>>(
      xb, Wb, (size_t)1048576, QKV, (size_t)(4096 * 1024), (const float*)nullptr,
      4096, 1024, 1024);

  attn_fused<<<dim3(32, 32), dim3(128), 0, stream>>>(
      QKV, QKV + 4096 * 1024, QKV + 2 * 4096 * 1024, Ob);

  // out = attn @ Wo^T + bo  (fp32 out)
  gemm_bt<1><<<dim3(8, 32, 1), dim3(256), 0, stream>>>(
      Ob, Wb + 3 * 1048576, (size_t)0, out, (size_t)0, bo, 4096, 1024, 1024);
}

// Round 3
// 175.883 us; speedup vs baseline: 1.2458x; 1.0272x over previous
//
#include <hip/hip_runtime.h>
#include <hip/hip_bf16.h>
#include <stdint.h>

// MHA fwd: B=2, N=2048, D=1024, H=16, HD=64, scale=0.125
#define B_ 2
#define N_ 2048
#define D_ 1024
#define H_ 16
#define SCALE_L2E 0.18033688011112042f  // 0.125 * log2(e): softmax in base-2 domain

typedef unsigned short u16;
typedef unsigned int u32;
using f32x4  = __attribute__((ext_vector_type(4))) float;
using f32x16 = __attribute__((ext_vector_type(16))) float;
using bf16x8 = __attribute__((ext_vector_type(8))) short;
using i16x8  = __attribute__((ext_vector_type(8))) short;

__device__ __forceinline__ u16 f2b(float f) {
  unsigned u = __float_as_uint(f);
  return (u16)((u + 0x7FFFu + ((u >> 16) & 1u)) >> 16);
}
__device__ __forceinline__ float b2f(short s) {
  return __uint_as_float(((u32)(u16)s) << 16);
}
__device__ __forceinline__ u32 pk2(float lo, float hi) {
  __hip_bfloat162 h = __float22bfloat162_rn(float2{lo, hi});
  return *reinterpret_cast<u32*>(&h);
}
__device__ __forceinline__ void async16(const u16* g, u16* l) {
  __builtin_amdgcn_global_load_lds(
      (const __attribute__((address_space(1))) void*)g,
      (__attribute__((address_space(3))) void*)l, 16, 0, 0);
}

__global__ __launch_bounds__(256) void cast8(const float* __restrict__ src,
                                             u16* __restrict__ dst, int n) {
  int i = (blockIdx.x * 256 + threadIdx.x) * 8;
  if (i >= n) return;
  i16x8 o;
#pragma unroll
  for (int j = 0; j < 8; ++j) o[j] = (short)f2b(src[i + j]);
  *(i16x8*)(dst + i) = o;
}

// all 4 weight casts in one launch (blockIdx.y selects)
__global__ __launch_bounds__(256) void cast_w(const float* __restrict__ w0,
                                              const float* __restrict__ w1,
                                              const float* __restrict__ w2,
                                              const float* __restrict__ w3,
                                              u16* __restrict__ dst) {
  const float* src = blockIdx.y == 0 ? w0 : blockIdx.y == 1 ? w1
                    : blockIdx.y == 2 ? w2 : w3;
  u16* d = dst + (size_t)blockIdx.y * 1048576;
  int i = (blockIdx.x * 256 + threadIdx.x) * 8;
  i16x8 o;
#pragma unroll
  for (int j = 0; j < 8; ++j) o[j] = (short)f2b(src[i + j]);
  *(i16x8*)(d + i) = o;
}

// C[M][Nn] = A[M][K] * Bt[Nn][K]^T. 128x128 tile, BK=32, 4 waves.
template <int F32OUT>
__global__ __launch_bounds__(256) void gemm_bt(
    const u16* __restrict__ A, const u16* __restrict__ Bt0, size_t sBz,
    void* __restrict__ C0, size_t sCz, const float* __restrict__ bias,
    int M, int Nn, int K) {
  __shared__ __align__(16) u16 As[128 * 32];
  __shared__ __align__(16) u16 Bs[128 * 32];
  const int tid = threadIdx.x;
  const int w = tid >> 6, l = tid & 63;
  const int wm = w >> 1, wn = w & 1;
  const int la = l & 15, lb = l >> 4;
  const int tM = blockIdx.y * 128, tN = blockIdx.x * 128;
  const u16* Bt = Bt0 + sBz * blockIdx.z;

  const int sr = (w << 4) + (l >> 2);
  const int sk = (l & 3) << 3;
  const u16* gA = A + (size_t)(tM + sr) * K + sk;
  const u16* gB = Bt + (size_t)(tN + sr) * K + sk;
  u16* lA = As + w * 512;
  u16* lB = Bs + w * 512;

  f32x4 acc[4][4] = {};

  for (int k0 = 0; k0 < K; k0 += 32) {
    async16(gA, lA);
    async16(gA + (size_t)64 * K, lA + 2048);
    async16(gB, lB);
    async16(gB + (size_t)64 * K, lB + 2048);
    gA += 32; gB += 32;
    __syncthreads();
    bf16x8 af[4], bfr[4];
#pragma unroll
    for (int i = 0; i < 4; ++i) {
      af[i]  = *(const bf16x8*)(As + (wm * 64 + i * 16 + la) * 32 + lb * 8);
      bfr[i] = *(const bf16x8*)(Bs + (wn * 64 + i * 16 + la) * 32 + lb * 8);
    }
#pragma unroll
    for (int i = 0; i < 4; ++i)
#pragma unroll
      for (int j = 0; j < 4; ++j)
        acc[i][j] = __builtin_amdgcn_mfma_f32_16x16x32_bf16(af[i], bfr[j], acc[i][j], 0, 0, 0);
    __syncthreads();
  }

  const float osc = (!F32OUT && blockIdx.z == 0) ? SCALE_L2E : 1.0f;
#pragma unroll
  for (int i = 0; i < 4; ++i) {
    const int row = tM + wm * 64 + i * 16 + lb * 4;
#pragma unroll
    for (int j = 0; j < 4; ++j) {
      const int col = tN + wn * 64 + j * 16 + la;
#pragma unroll
      for (int r = 0; r < 4; ++r) {
        const float v = acc[i][j][r];
        if (F32OUT) {
          ((float*)C0)[(size_t)(row + r) * Nn + col] = v + bias[col];
        } else {
          (((u16*)C0) + sCz * blockIdx.z)[(size_t)(row + r) * Nn + col] = f2b(v * osc);
        }
      }
    }
  }
}

// V [B*N][D] (per-head cols) -> VtG [(b*16+h)*64 + d][N]  (one-shot transpose)
__global__ __launch_bounds__(256) void vtrans(const u16* __restrict__ V,
                                              u16* __restrict__ Vt) {
  __shared__ u16 T[64][72];
  const int tid = threadIdx.x;
  const int rt = blockIdx.x, h = blockIdx.y;
  const int r = tid >> 3, c = (tid & 7) * 8;
#pragma unroll
  for (int p = 0; p < 2; ++p) {
    i16x8 v = *(const i16x8*)(V + (size_t)(rt * 64 + p * 32 + r) * D_ + h * 64 + c);
#pragma unroll
    for (int j = 0; j < 8; ++j) T[p * 32 + r][c + j] = (u16)v[j];
  }
  __syncthreads();
  const int b = rt >> 5, nb = (rt & 31) * 64;
#pragma unroll
  for (int p = 0; p < 2; ++p) {
    const int d = p * 32 + r;
    i16x8 o;
#pragma unroll
    for (int j = 0; j < 8; ++j) o[j] = (short)T[c + j][d];
    *(i16x8*)(Vt + ((size_t)((b * 16 + h) * 64 + d)) * (size_t)N_ + nb + c) = o;
  }
}

// Flash attention, swapped-QK^T 32x32, split-KV x2, double-buffered LDS.
// grid (N/128, B*H, 2), 256 thr = 4 waves x 32 queries. KV tile 64.
__global__ __launch_bounds__(256) void attn_fused(
    const u16* __restrict__ Q, const u16* __restrict__ Kb,
    const u16* __restrict__ VtG, u16* __restrict__ On0, u16* __restrict__ On1,
    float2* __restrict__ ML) {
  __shared__ __align__(16) u16 Ks[2 * 64 * 64];  // [buf][key][d], swizzled
  __shared__ __align__(16) u16 Vs[2 * 64 * 64];  // [buf][d][key], swizzled
  const int tid = threadIdx.x;
  const int w = tid >> 6, l = tid & 63;
  const int q = l & 31, hi = l >> 5;
  const int y = blockIdx.y;
  const int b = y >> 4, h = y & 15;
  const int q0 = blockIdx.x * 128 + w * 32;
  const int sp = blockIdx.z;
  const int kvbase = sp * (N_ / 2);

  const u16* Qrow = Q + (size_t)(b * N_ + q0 + q) * D_ + h * 64;
  bf16x8 qf[4];
#pragma unroll
  for (int s = 0; s < 4; ++s) qf[s] = *(const bf16x8*)(Qrow + s * 16 + hi * 8);

  // staging addressing (swizzle applied on global source; LDS dest linear)
  const int srow = l >> 3;                       // 0..7
  const int scol = ((l & 7) ^ srow) << 3;        // pre-swizzled col (elems)
  const int krow = w * 16 + srow;
  const u16* Kg = Kb + (size_t)(b * N_ + kvbase + krow) * D_ + h * 64 + scol;
  const u16* Vg = VtG + (size_t)(y * 64 + w * 16 + srow) * N_ + kvbase + scol;

  const int qsw = (q & 7) << 3;
  const int qr0 = q * 64, qr1 = (32 + q) * 64;

  float m_r = -1e30f, l_r = 0.f;
  f32x16 o0 = {}, o1 = {};

  auto stage = [&](int t, int buf) {
    const u16* kg = Kg + (size_t)(t * 64) * D_;
    u16* kd = Ks + buf * 4096 + w * 1024;
    async16(kg, kd);
    async16(kg + (size_t)8 * D_, kd + 512);
    const u16* vg = Vg + t * 64;
    u16* vd = Vs + buf * 4096 + w * 1024;
    async16(vg, vd);
    async16(vg + (size_t)8 * N_, vd + 512);
  };

  const int NT = (N_ / 2) / 64;  // 16
  stage(0, 0);
  __syncthreads();

  for (int t = 0; t < NT; ++t) {
    const int buf = t & 1;
    if (t + 1 < NT) stage(t + 1, buf ^ 1);
    const u16* KT = Ks + buf * 4096;
    const u16* VT = Vs + buf * 4096;

    // S^T = K Q^T
    f32x16 p0 = {}, p1 = {};
    __builtin_amdgcn_s_setprio(1);
#pragma unroll
    for (int s = 0; s < 4; ++s) {
      const int off = (s * 16 + hi * 8) ^ qsw;
      bf16x8 kf0 = *(const bf16x8*)(KT + qr0 + off);
      bf16x8 kf1 = *(const bf16x8*)(KT + qr1 + off);
      p0 = __builtin_amdgcn_mfma_f32_32x32x16_bf16(kf0, qf[s], p0, 0, 0, 0);
      p1 = __builtin_amdgcn_mfma_f32_32x32x16_bf16(kf1, qf[s], p1, 0, 0, 0);
    }
    __builtin_amdgcn_s_setprio(0);

    // online softmax (log2 domain), tree reductions
    float tr[16];
#pragma unroll
    for (int i = 0; i < 16; ++i) tr[i] = fmaxf(p0[i], p1[i]);
#pragma unroll
    for (int st = 8; st > 0; st >>= 1)
#pragma unroll
      for (int i = 0; i < st; ++i) tr[i] = fmaxf(tr[i], tr[i + st]);
    float pm = fmaxf(tr[0], __shfl_xor(tr[0], 32, 64));
    if (__any(pm > m_r + 8.f)) {  // T13 defer-max
      const float mn = fmaxf(m_r, pm);
      const float alpha = exp2f(m_r - mn);
      m_r = mn;
      l_r *= alpha;
#pragma unroll
      for (int r = 0; r < 16; ++r) { o0[r] *= alpha; o1[r] *= alpha; }
    }
#pragma unroll
    for (int r = 0; r < 16; ++r) p0[r] = exp2f(p0[r] - m_r);
#pragma unroll
    for (int r = 0; r < 16; ++r) p1[r] = exp2f(p1[r] - m_r);
#pragma unroll
    for (int i = 0; i < 16; ++i) tr[i] = p0[i] + p1[i];
#pragma unroll
    for (int st = 8; st > 0; st >>= 1)
#pragma unroll
      for (int i = 0; i < st; ++i) tr[i] += tr[i + st];
    l_r += tr[0] + __shfl_xor(tr[0], 32, 64);

    // pack P -> PV B-frags (cvt_pk + half-exchange)
    u32 pw[4][4];
#pragma unroll
    for (int ks = 0; ks < 4; ++ks) {
      const f32x16& P = (ks < 2) ? p0 : p1;
      const int rb = (ks & 1) * 8;
      const u32 A0 = pk2(P[rb + 0], P[rb + 1]);
      const u32 B0 = pk2(P[rb + 2], P[rb + 3]);
      const u32 A1 = pk2(P[rb + 4], P[rb + 5]);
      const u32 B1 = pk2(P[rb + 6], P[rb + 7]);
      const u32 v1 = hi ? A0 : A1, v2 = hi ? B0 : B1;
      const u32 sv1 = (u32)__shfl_xor((int)v1, 32, 64);
      const u32 sv2 = (u32)__shfl_xor((int)v2, 32, 64);
      pw[ks][0] = hi ? sv1 : A0;  pw[ks][1] = hi ? sv2 : B0;
      pw[ks][2] = hi ? A1 : sv1;  pw[ks][3] = hi ? B1 : sv2;
    }

    // O^T += V^T P^T
    __builtin_amdgcn_s_setprio(1);
#pragma unroll
    for (int ks = 0; ks < 4; ++ks) {
      union { u32 u[4]; bf16x8 v; } pb;
#pragma unroll
      for (int j = 0; j < 4; ++j) pb.u[j] = pw[ks][j];
      const int off = (ks * 16 + hi * 8) ^ qsw;
      bf16x8 va0 = *(const bf16x8*)(VT + qr0 + off);
      bf16x8 va1 = *(const bf16x8*)(VT + qr1 + off);
      o0 = __builtin_amdgcn_mfma_f32_32x32x16_bf16(va0, pb.v, o0, 0, 0, 0);
      o1 = __builtin_amdgcn_mfma_f32_32x32x16_bf16(va1, pb.v, o1, 0, 0, 0);
    }
    __builtin_amdgcn_s_setprio(0);
    __syncthreads();  // drains vmcnt (next tile staged) + LDS reuse safety
  }

  // epilogue: normalized partial + (m,l)
  const float inv = 1.f / l_r;
  u16* Ob = (sp ? On1 : On0) + (size_t)(b * N_ + q0 + q) * D_ + h * 64;
#pragma unroll
  for (int rh = 0; rh < 4; ++rh) {
    uint2 s0, s1;
    s0.x = pk2(o0[4 * rh + 0] * inv, o0[4 * rh + 1] * inv);
    s0.y = pk2(o0[4 * rh + 2] * inv, o0[4 * rh + 3] * inv);
    s1.x = pk2(o1[4 * rh + 0] * inv, o1[4 * rh + 1] * inv);
    s1.y = pk2(o1[4 * rh + 2] * inv, o1[4 * rh + 3] * inv);
    *(uint2*)(Ob + 8 * rh + 4 * hi)      = s0;
    *(uint2*)(Ob + 32 + 8 * rh + 4 * hi) = s1;
  }
  if (hi == 0) ML[sp * (B_ * H_ * N_) + y * N_ + q0 + q] = make_float2(m_r, l_r);
}

// combine the two KV-split partials: Ob = w0*P0 + w1*P1 (in place on P0)
__global__ __launch_bounds__(256) void combine(const u16* __restrict__ P1,
                                               u16* __restrict__ P0io,
                                               const float2* __restrict__ ML) {
  const int idx = blockIdx.x * 256 + threadIdx.x;  // 524288 threads
  const size_t e0 = (size_t)idx * 8;
  const int row = idx >> 7;            // (b,n) 0..4095
  const int h = (idx & 127) >> 3;      // col0 = (idx&127)*8; h = col0/64
  const int b = row >> 11, n = row & 2047;
  const int mi = (b * H_ + h) * N_ + n;
  const float2 ml0 = ML[mi];
  const float2 ml1 = ML[B_ * H_ * N_ + mi];
  const float m = fmaxf(ml0.x, ml1.x);
  float a0 = exp2f(ml0.x - m) * ml0.y;
  float a1 = exp2f(ml1.x - m) * ml1.y;
  const float inv = 1.f / (a0 + a1);
  a0 *= inv; a1 *= inv;
  i16x8 v0 = *(const i16x8*)(P0io + e0);
  i16x8 v1 = *(const i16x8*)(P1 + e0);
  i16x8 o;
#pragma unroll
  for (int j = 0; j < 8; ++j) o[j] = (short)f2b(a0 * b2f(v0[j]) + a1 * b2f(v1[j]));
  *(i16x8*)(P0io + e0) = o;
}

extern "C" void kernel_launch(void* const* d_in, const int* in_sizes, int n_in,
                              void* d_out, int out_size, void* d_ws, size_t ws_size,
                              hipStream_t stream) {
  const float* x  = (const float*)d_in[0];
  const float* Wq = (const float*)d_in[1];
  const float* Wk = (const float*)d_in[2];
  const float* Wv = (const float*)d_in[3];
  const float* Wo = (const float*)d_in[4];
  const float* bo = (const float*)d_in[5];
  float* out = (float*)d_out;

  char* ws = (char*)d_ws;
  u16* xb   = (u16*)(ws);                   // 8 MiB: x bf16; reused as VtG after GEMM
  u16* Wb   = (u16*)(ws + (8ull << 20));    // 8 MiB: Wq,Wk,Wv,Wo bf16
  u16* QKV  = (u16*)(ws + (16ull << 20));   // 24 MiB: Q,K,V bf16
  u16* Ob   = (u16*)(ws + (40ull << 20));   // 8 MiB: attn out / split-0 partial
  u16* VtG  = xb;                           // transposed V (xb dead after QKV GEMM)
  u16* Op1  = QKV + 2 * 4096 * 1024;        // split-1 partial (V slot, dead after vtrans)
  float2* ML = (float2*)Wb;                 // 1 MiB (Wq slot, dead after QKV GEMM)

  cast8<<<dim3(2048), dim3(256), 0, stream>>>(x, xb, 4096 * 1024);
  cast_w<<<dim3(512, 4), dim3(256), 0, stream>>>(Wq, Wk, Wv, Wo, Wb);

  gemm_bt<0><<<dim3(8, 32, 3), dim3(256), 0, stream>>>(
      xb, Wb, (size_t)1048576, QKV, (size_t)(4096 * 1024), (const float*)nullptr,
      4096, 1024, 1024);

  vtrans<<<dim3(64, 16), dim3(256), 0, stream>>>(QKV + 2 * 4096 * 1024, VtG);

  attn_fused<<<dim3(16, 32, 2), dim3(256), 0, stream>>>(
      QKV, QKV + 4096 * 1024, VtG, Ob, Op1, ML);

  combine<<<dim3(2048), dim3(256), 0, stream>>>(Op1, Ob, ML);

  gemm_bt<1><<<dim3(8, 32, 1), dim3(256), 0, stream>>>(
      Ob, Wb + 3 * 1048576, (size_t)0, out, (size_t)0, bo, 4096, 1024, 1024);
}